// Round 5
// baseline (127.163 us; speedup 1.0000x reference)
//
#include <hip/hip_runtime.h>

#define B_ 4
#define N_ 1024
#define H_ 256

// ---------- ws layout (bytes) ----------
// wout f32 [4][256][1024] @ 0        (4194304)   scan output [b][h][de]; overlays w_hi/w_lo
//   w_hi bf16 [896][256]  @ 0        (458752)    dead after proj
//   w_lo bf16 [896][256]  @ 458752   (458752)    dead after proj
// kvb  f32  [4][1024][64] @ 4194304  (1048576)
// dd   f32  [4][1024][32] @ 5242880  (524288)
// kh   bf16 [4][256][1024]@ 5767168  (2097152)
// vh   bf16 [4][256][1024]@ 7864320  (2097152)
// dh   f32  [4][256][1024]@ 9961472  (4194304)
// tok_hi/tok_lo bf16 (2MB+2MB) live in d_out; dead after mfma_proj.

typedef __attribute__((ext_vector_type(8))) short bf16x8;
typedef __attribute__((ext_vector_type(4))) float f32x4;
typedef __attribute__((ext_vector_type(16))) float f32x16;

__device__ __forceinline__ short f2bf(float x) {
  union { float f; unsigned u; } c; c.f = x;
  unsigned r = (c.u + 0x7FFFu + ((c.u >> 16) & 1u)) >> 16;
  return (short)r;
}
__device__ __forceinline__ float bf2f(short s) {
  union { unsigned u; float f; } c; c.u = ((unsigned)(unsigned short)s) << 16;
  return c.f;
}
__device__ __forceinline__ float rcp_fast(float x) {
#if __has_builtin(__builtin_amdgcn_rcpf)
  return __builtin_amdgcn_rcpf(x);
#else
  return 1.0f / x;
#endif
}
__device__ __forceinline__ float sigm(float x) { return rcp_fast(1.0f + __expf(-x)); }
__device__ __forceinline__ unsigned cvt_pk_bf16(float lo, float hi) {
  unsigned r;
  asm("v_cvt_pk_bf16_f32 %0, %1, %2" : "=v"(r) : "v"(lo), "v"(hi));
  return r;
}

// ---------------- Kernel 1: f32 -> bf16 hi/lo conversion ----------------
__global__ __launch_bounds__(256) void convert_all(
    const float* __restrict__ token,
    const float* __restrict__ Wkv, const float* __restrict__ Wkvh,
    const float* __restrict__ Wdec, const float* __restrict__ Wdech,
    short* __restrict__ tok_hi, short* __restrict__ tok_lo,
    short* __restrict__ w_hi, short* __restrict__ w_lo)
{
  const int bid = blockIdx.x, tid = threadIdx.x;
  if (bid < 1024) {
    const int idx = bid * 256 + tid;                 // float4 index, 262144 total
    const float4 x = reinterpret_cast<const float4*>(token)[idx];
    short4 h, l;
    h.x = f2bf(x.x); l.x = f2bf(x.x - bf2f(h.x));
    h.y = f2bf(x.y); l.y = f2bf(x.y - bf2f(h.y));
    h.z = f2bf(x.z); l.z = f2bf(x.z - bf2f(h.z));
    h.w = f2bf(x.w); l.w = f2bf(x.w - bf2f(h.w));
    reinterpret_cast<short4*>(tok_hi)[idx] = h;
    reinterpret_cast<short4*>(tok_lo)[idx] = l;
  } else {
    const int c = bid - 1024;                        // output column 0..895
    const int k = tid;
    float s = 0.0f;
    if (c < 64)       s = Wkv[k * 64 + c];
    else if (c < 576) s = Wkvh[k * 512 + (c - 64)];
    else if (c < 608) s = Wdec[k * 32 + (c - 576)];
    else if (c < 864) s = Wdech[k * 256 + (c - 608)];
    const short h = f2bf(s);
    const short l = f2bf(s - bf2f(h));
    w_hi[c * 256 + k] = h;
    w_lo[c * 256 + k] = l;
  }
}

// ---------------- Kernel 2: MFMA projection GEMM (128x128, 2-phase dbuf) ----------------
// C(4096x896) = [t_hi | t_lo | t_hi](4096x768) @ [W_hi ; W_hi ; W_lo](768x896)
__global__ __launch_bounds__(256) void mfma_proj(
    const short* __restrict__ tok_hi, const short* __restrict__ tok_lo,
    const short* __restrict__ w_hi, const short* __restrict__ w_lo,
    float* __restrict__ kvb, float* __restrict__ dd,
    short* __restrict__ kh, short* __restrict__ vh, float* __restrict__ dh)
{
  __shared__ __align__(16) char smem[66816];   // staging 64KB | reused: Cs f32[128][130]
  // buffers: A0 @0, A1 @16384, B0 @32768, B1 @49152 (offsets computed inline)

  const int tid = threadIdx.x;
  const int lane = tid & 63;
  const int wid = tid >> 6;
  const int wrow = (wid >> 1) * 64;
  const int wcol = (wid & 1) * 64;
  const int R0b = blockIdx.x * 128;
  const int C0b = blockIdx.y * 128;

  const int lrow = tid >> 3;                  // 0..31 (8 threads/row)
  const int wb = (tid & 7) * 16;              // 16B slot in 128B row
  const int swb = wb ^ ((lrow & 7) << 4);     // T2 swizzle (row&7 invariant under +32)

  f32x4 acc[4][4];
#pragma unroll
  for (int mi = 0; mi < 4; ++mi)
#pragma unroll
    for (int ni = 0; ni < 4; ++ni)
#pragma unroll
      for (int r = 0; r < 4; ++r) acc[mi][ni][r] = 0.0f;

  float4 ra[4], rb[4];
  // prolog: load + write step 0 into buf0
  {
    const char* As = (const char*)tok_hi;
    const char* Bs = (const char*)w_hi;
#pragma unroll
    for (int i = 0; i < 4; ++i) {
      const int row = i * 32 + lrow;
      ra[i] = *reinterpret_cast<const float4*>(As + (size_t)(R0b + row) * 512 + wb);
      rb[i] = *reinterpret_cast<const float4*>(Bs + (size_t)(C0b + row) * 512 + wb);
    }
#pragma unroll
    for (int i = 0; i < 4; ++i) {
      *reinterpret_cast<float4*>(smem + (i * 32 + lrow) * 128 + swb) = ra[i];
      *reinterpret_cast<float4*>(smem + 32768 + (i * 32 + lrow) * 128 + swb) = rb[i];
    }
  }

#pragma unroll 1
  for (int s = 0; s < 12; ++s) {
    const int nxt = s + 1;
    if (nxt < 12) {                           // issue next-step loads (hide under MFMA)
      const int seg = nxt >> 2, k0b = (nxt & 3) * 128;
      const char* As = (seg == 1) ? (const char*)tok_lo : (const char*)tok_hi;
      const char* Bs = (seg == 2) ? (const char*)w_lo : (const char*)w_hi;
#pragma unroll
      for (int i = 0; i < 4; ++i) {
        const int row = i * 32 + lrow;
        ra[i] = *reinterpret_cast<const float4*>(As + (size_t)(R0b + row) * 512 + k0b + wb);
        rb[i] = *reinterpret_cast<const float4*>(Bs + (size_t)(C0b + row) * 512 + k0b + wb);
      }
    }
    __syncthreads();                          // buf[s&1] ready; buf[nxt&1] free
    {
      const int co = (s & 1) << 14;           // 0 or 16384
      const char* A = smem + co;
      const char* Bb = smem + 32768 + co;
#pragma unroll
      for (int ks = 0; ks < 2; ++ks) {
        bf16x8 a[4], b[4];
        const int rb2 = ks * 64 + (lane >> 4) * 16;
#pragma unroll
        for (int mi = 0; mi < 4; ++mi) {
          const int row = wrow + mi * 16 + (lane & 15);
          a[mi] = *reinterpret_cast<const bf16x8*>(A + row * 128 + (rb2 ^ ((row & 7) << 4)));
        }
#pragma unroll
        for (int ni = 0; ni < 4; ++ni) {
          const int col = wcol + ni * 16 + (lane & 15);
          b[ni] = *reinterpret_cast<const bf16x8*>(Bb + col * 128 + (rb2 ^ ((col & 7) << 4)));
        }
#pragma unroll
        for (int mi = 0; mi < 4; ++mi)
#pragma unroll
          for (int ni = 0; ni < 4; ++ni)
            acc[mi][ni] = __builtin_amdgcn_mfma_f32_16x16x32_bf16(a[mi], b[ni], acc[mi][ni], 0, 0, 0);
      }
    }
    if (nxt < 12) {                           // vmcnt auto-inserted before these writes
      const int no = (nxt & 1) << 14;
#pragma unroll
      for (int i = 0; i < 4; ++i) {
        *reinterpret_cast<float4*>(smem + no + (i * 32 + lrow) * 128 + swb) = ra[i];
        *reinterpret_cast<float4*>(smem + 32768 + no + (i * 32 + lrow) * 128 + swb) = rb[i];
      }
    }
  }

  // ---- Epilogue ----
  const int b = R0b >> 10;
  const int nb = R0b & (N_ - 1);

  // direct coalesced frag stores for kvb (cols 0..63) and dd (cols 576..607)
#pragma unroll
  for (int mi = 0; mi < 4; ++mi) {
    const int n = nb + wrow + mi * 16 + (lane >> 4) * 4;
#pragma unroll
    for (int ni = 0; ni < 4; ++ni) {
      const int cb = C0b + wcol + ni * 16;
      const int col = cb + (lane & 15);
      const f32x4 v = acc[mi][ni];
      if (cb < 64) {
#pragma unroll
        for (int r = 0; r < 4; ++r)
          kvb[((size_t)(b << 10) + n + r) * 64 + col] = v[r];
      } else if (cb >= 576 && cb < 608) {
#pragma unroll
        for (int r = 0; r < 4; ++r)
          dd[((size_t)(b << 10) + n + r) * 32 + (col - 576)] = v[r];
      }
    }
  }

  __syncthreads();                            // staging LDS dead -> reuse as Cs
  float* Cs = (float*)smem;                   // [128][130]
#pragma unroll
  for (int mi = 0; mi < 4; ++mi)
#pragma unroll
    for (int ni = 0; ni < 4; ++ni) {
      const int col = wcol + ni * 16 + (lane & 15);
      const int rowb = wrow + mi * 16 + (lane >> 4) * 4;
#pragma unroll
      for (int r = 0; r < 4; ++r) Cs[(rowb + r) * 130 + col] = acc[mi][ni][r];
    }
  __syncthreads();

  // column stores: thread t -> col t>>1, rows half*64..half*64+63 (contiguous in dst)
  {
    const int cloc = tid >> 1, half = tid & 1;
    const int gc = C0b + cloc;
    const int n0 = nb + half * 64;
    const int rbase = half * 64;
    if (gc >= 64 && gc < 576) {               // kh / vh, bf16, 128B contiguous
      short* dst = (gc < 320)
          ? kh + (((size_t)(b * H_ + (gc - 64))) << 10) + n0
          : vh + (((size_t)(b * H_ + (gc - 320))) << 10) + n0;
#pragma unroll
      for (int j0 = 0; j0 < 64; j0 += 8) {
        union { short s[8]; int4 q; } u;
#pragma unroll
        for (int jj = 0; jj < 8; ++jj)
          u.s[jj] = f2bf(Cs[(rbase + j0 + jj) * 130 + cloc]);
        *reinterpret_cast<int4*>(dst + j0) = u.q;
      }
    } else if (gc >= 608 && gc < 864) {       // dh, f32, 256B contiguous
      float* dst = dh + (((size_t)(b * H_ + (gc - 608))) << 10) + n0;
#pragma unroll
      for (int j0 = 0; j0 < 64; j0 += 4) {
        float4 q;
        q.x = Cs[(rbase + j0 + 0) * 130 + cloc];
        q.y = Cs[(rbase + j0 + 1) * 130 + cloc];
        q.z = Cs[(rbase + j0 + 2) * 130 + cloc];
        q.w = Cs[(rbase + j0 + 3) * 130 + cloc];
        *reinterpret_cast<float4*>(dst + j0) = q;
      }
    }
  }
}

// ---------------- Kernel 3: decay scan + MFMA outer product ----------------
// One block per (b,h). weight[i] = prod_{u=1..i} sigmoid(decay[N-u]) -> exact-0 fast.
__device__ float chunk_prod(int c, const float* __restrict__ dd,
                            const float* __restrict__ dh_lds, int d, int grp) {
  float p0 = 1.0f, p1 = 1.0f;
#pragma unroll
  for (int s = 0; s < 32; s += 2) {
    const int iA = c * 64 + 2 * s + grp;      // c>=7 -> iA>0 always
    const int iB = iA + 2;
    p0 *= sigm(dd[(N_ - iA) * 32 + d] * dh_lds[N_ - iA]);
    p1 *= sigm(dd[(N_ - iB) * 32 + d] * dh_lds[N_ - iB]);
  }
  float p = p0 * p1;
  p *= __shfl_xor(p, 32, 64);
  return p;
}

__global__ __launch_bounds__(256) void scan_outer(
    const float* __restrict__ kvb_all, const float* __restrict__ dd_all,
    const short* __restrict__ kh_all, const short* __restrict__ vh_all,
    const float* __restrict__ dh_all, float* __restrict__ wout)
{
  const int bh = blockIdx.x;
  const int b = bh >> 8, h = bh & (H_ - 1);
  const int tid = threadIdx.x;
  const int w = tid >> 6, lane = tid & 63;
  const int d = lane & 31, grp = lane >> 5;

  const float* kvb = kvb_all + (size_t)b * (N_ * 64);
  const float* dd  = dd_all + (size_t)b * (N_ * 32);
  const short* khp = kh_all + ((size_t)(b * H_ + h) << 10);
  const short* vhp = vh_all + ((size_t)(b * H_ + h) << 10);
  const float* dhp = dh_all + ((size_t)(b * H_ + h) << 10);

  __shared__ float dh_lds[1024];
  __shared__ short kh_lds[1024], vh_lds[1024];
  __shared__ float q_lds[7 * 32];
  __shared__ int dead_s[8];
  __shared__ float acc_lds[4][1024];

  // stage per-head columns (coalesced)
  for (int idx = tid; idx < 1024; idx += 256) dh_lds[idx] = dhp[idx];
  for (int idx = tid; idx < 512; idx += 256) {
    ((int*)kh_lds)[idx] = ((const int*)khp)[idx];
    ((int*)vh_lds)[idx] = ((const int*)vhp)[idx];
  }
  __syncthreads();

  // Phase 1: Q[c] for c=0..6 only (wave w: c=w, w+4 if <7). 2-acc tree product.
  for (int c = w; c < 7; c += 4) {
    float p0 = 1.0f, p1 = 1.0f;
#pragma unroll
    for (int s = 0; s < 32; s += 2) {
      const int iA = c * 64 + 2 * s + grp;
      const int iB = iA + 2;
      if (iA > 0) p0 *= sigm(dd[(N_ - iA) * 32 + d] * dh_lds[N_ - iA]);
      p1 *= sigm(dd[(N_ - iB) * 32 + d] * dh_lds[N_ - iB]);
    }
    float p = p0 * p1;
    p *= __shfl_xor(p, 32, 64);
    if (lane < 32) q_lds[c * 32 + d] = p;
  }
  __syncthreads();

  f32x16 acc;
#pragma unroll
  for (int r = 0; r < 16; ++r) acc[r] = 0.0f;

  float C = 1.0f;
  for (int j = 0; j < w; ++j) C *= q_lds[j * 32 + d];    // w<=3 -> Q[0..2]

#pragma unroll 1
  for (int r = 0; r < 4; ++r) {
    const int c = 4 * r + w;
    const int par = (r & 1) * 4;
    const bool my_dead = __all(C == 0.0f);
    if (lane == 0) dead_s[par + w] = my_dead ? 1 : 0;
    __syncthreads();
    if (dead_s[par] && dead_s[par + 1] && dead_s[par + 2] && dead_s[par + 3]) break;
    if (!my_dead) {
      float Cc = C;
#pragma unroll 1
      for (int t = 0; t < 4; ++t) {
        const int base = c * 64 + t * 16 + grp * 8;      // my 8 rows
        float xk[8], xv[8], dx[8];
#pragma unroll
        for (int j = 0; j < 8; ++j) {
          const int n = base + j;
          xk[j] = kvb[n * 64 + d] * bf2f(kh_lds[n]);
          xv[j] = kvb[n * 64 + 32 + d] * bf2f(vh_lds[n]);
          const int mr = (n == 0) ? 1 : (N_ - n);
          dx[j] = dd[mr * 32 + d] * dh_lds[mr];
        }
        float p[8];
        p[0] = (base == 0) ? 1.0f : sigm(dx[0]);
#pragma unroll
        for (int j = 1; j < 8; ++j) p[j] = p[j - 1] * sigm(dx[j]);
        const float tot = p[7];
        const float oth = __shfl_xor(tot, 32, 64);
        const float pre = Cc * (grp ? oth : 1.0f);
        union { unsigned u[4]; bf16x8 v; } A, Bv;
#pragma unroll
        for (int jj = 0; jj < 4; ++jj) {
          const int j0 = 2 * jj, j1 = 2 * jj + 1;
          const float a0 = xk[j0] * sigm(xk[j0]) * (pre * p[j0]);
          const float a1 = xk[j1] * sigm(xk[j1]) * (pre * p[j1]);
          const float b0 = xv[j0] * sigm(xv[j0]);
          const float b1 = xv[j1] * sigm(xv[j1]);
          A.u[jj] = cvt_pk_bf16(a0, a1);
          Bv.u[jj] = cvt_pk_bf16(b0, b1);
        }
        Cc *= tot * oth;
        acc = __builtin_amdgcn_mfma_f32_32x32x16_bf16(A.v, Bv.v, acc, 0, 0, 0);
      }
    }
    if (r < 3) {
      if (__any(C != 0.0f)) {                 // wave-uniform; chunk_prod is collective
#pragma unroll 1
        for (int j = 0; j < 4; ++j) {
          const int cc = c + j;               // <= 14
          const float q = (cc < 7) ? q_lds[cc * 32 + d] : chunk_prod(cc, dd, dh_lds, d, grp);
          C *= q;
        }
      }
    }
  }

  // Combine 4 wave partials. 32x32 C/D: col=lane&31, row=(reg&3)+8*(reg>>2)+4*grp.
#pragma unroll
  for (int rg = 0; rg < 16; ++rg) {
    const int m = (rg & 3) + 8 * (rg >> 2) + 4 * grp;
    acc_lds[w][m * 32 + d] = acc[rg];
  }
  __syncthreads();
  {
    const int el = tid * 4;
    const float4 s0 = *reinterpret_cast<const float4*>(&acc_lds[0][el]);
    const float4 s1 = *reinterpret_cast<const float4*>(&acc_lds[1][el]);
    const float4 s2 = *reinterpret_cast<const float4*>(&acc_lds[2][el]);
    const float4 s3 = *reinterpret_cast<const float4*>(&acc_lds[3][el]);
    float4 st;
    st.x = s0.x + s1.x + s2.x + s3.x;
    st.y = s0.y + s1.y + s2.y + s3.y;
    st.z = s0.z + s1.z + s2.z + s3.z;
    st.w = s0.w + s1.w + s2.w + s3.w;
    *reinterpret_cast<float4*>(&wout[(((size_t)(b * H_ + h)) << 10) + el]) = st;
  }
}

// ---------------- Kernel 4: transpose [b][h][de] -> out[b][de][h] ----------------
__global__ __launch_bounds__(256) void out_transpose(const float* __restrict__ wout,
                                                     float* __restrict__ out)
{
  __shared__ float T[64][65];
  const int bid = blockIdx.x;            // 256 blocks: b(4) x de_t(16) x h_t(4)
  const int b = bid >> 6, de_t = (bid >> 2) & 15, h_t = bid & 3;
  const int de0 = de_t * 64, h0 = h_t * 64;
  const int tid = threadIdx.x;
  const float* src = wout + (size_t)b * (H_ * N_);
  float* dst = out + (size_t)b * (N_ * H_);

#pragma unroll
  for (int q = 0; q < 4; ++q) {
    const int idx = q * 256 + tid;
    const int rh = idx >> 4, c4 = idx & 15;
    const float4 v = *reinterpret_cast<const float4*>(&src[(h0 + rh) * N_ + de0 + c4 * 4]);
    T[c4 * 4 + 0][rh] = v.x; T[c4 * 4 + 1][rh] = v.y;
    T[c4 * 4 + 2][rh] = v.z; T[c4 * 4 + 3][rh] = v.w;
  }
  __syncthreads();
#pragma unroll
  for (int q = 0; q < 4; ++q) {
    const int idx = q * 256 + tid;
    const int rd = idx >> 4, c4 = idx & 15;
    float4 v;
    v.x = T[rd][c4 * 4 + 0]; v.y = T[rd][c4 * 4 + 1];
    v.z = T[rd][c4 * 4 + 2]; v.w = T[rd][c4 * 4 + 3];
    *reinterpret_cast<float4*>(&dst[(de0 + rd) * H_ + h0 + c4 * 4]) = v;
  }
}

extern "C" void kernel_launch(void* const* d_in, const int* in_sizes, int n_in,
                              void* d_out, int out_size, void* d_ws, size_t ws_size,
                              hipStream_t stream) {
  const float* token = (const float*)d_in[0];
  const float* Wkv   = (const float*)d_in[1];
  const float* Wkvh  = (const float*)d_in[2];
  const float* Wdec  = (const float*)d_in[3];
  const float* Wdech = (const float*)d_in[4];
  float* out = (float*)d_out;

  short* tok_hi = (short*)d_out;          // d_out as scratch (4MB exactly)
  short* tok_lo = tok_hi + 1048576;

  char* wsb = (char*)d_ws;
  float* wout = (float*)(wsb + 0);        // overlays w_hi/w_lo (dead after proj)
  short* w_hi = (short*)(wsb + 0);
  short* w_lo = (short*)(wsb + 458752);
  float* kvb  = (float*)(wsb + 4194304);
  float* dd   = (float*)(wsb + 5242880);
  short* kh   = (short*)(wsb + 5767168);
  short* vh   = (short*)(wsb + 7864320);
  float* dh   = (float*)(wsb + 9961472);

  convert_all<<<1920, 256, 0, stream>>>(token, Wkv, Wkvh, Wdec, Wdech,
                                        tok_hi, tok_lo, w_hi, w_lo);
  mfma_proj<<<dim3(32, 7), 256, 0, stream>>>(tok_hi, tok_lo, w_hi, w_lo,
                                             kvb, dd, kh, vh, dh);
  scan_outer<<<B_ * H_, 256, 0, stream>>>(kvb, dd, kh, vh, dh, wout);
  out_transpose<<<256, 256, 0, stream>>>(wout, out);
}